// Round 5
// baseline (599.036 us; speedup 1.0000x reference)
//
#include <hip/hip_runtime.h>
#include <stdint.h>

#define B_ROWS 4096
#define N_FEAT 32768
#define K_DIM  1024
#define BM 256
#define BN 256
#define NT2 (N_FEAT / BN)   // 128 n-tiles
#define NKT (K_DIM / 64)    // 16 K-tiles

typedef __attribute__((ext_vector_type(8))) short bf16x8;
typedef __attribute__((ext_vector_type(4))) float f32x4;
typedef __attribute__((address_space(1))) unsigned char ga_u8;
typedef __attribute__((address_space(3))) unsigned char lds_u8;

__device__ inline unsigned short f2bf(float f) {
  union { float f; unsigned u; } v; v.f = f;
  unsigned r = v.u + 0x7FFF + ((v.u >> 16) & 1);
  return (unsigned short)(r >> 16);
}
__device__ inline float bf2f(unsigned short u) {
  union { unsigned u; float f; } v; v.u = ((unsigned)u) << 16;
  return v.f;
}

// ---------------- K0: fused {normalize+cast inputs} and {cast features} ----------
__global__ void k_prep(const float* __restrict__ in, unsigned short* __restrict__ xbf,
                       const float* __restrict__ f, unsigned short* __restrict__ fbf) {
  int bid = blockIdx.x;
  int t = threadIdx.x;
  if (bid < B_ROWS) {
    // normalize one input row, cast to bf16
    int row = bid;
    float4 v = reinterpret_cast<const float4*>(in + (size_t)row * K_DIM)[t];
    float ssq = v.x * v.x + v.y * v.y + v.z * v.z + v.w * v.w;
    #pragma unroll
    for (int d = 1; d < 64; d <<= 1) ssq += __shfl_xor(ssq, d);
    __shared__ float sm[4];
    if ((t & 63) == 0) sm[t >> 6] = ssq;
    __syncthreads();
    float nrm = sqrtf(sm[0] + sm[1] + sm[2] + sm[3]);
    float inv = 1.0f / fmaxf(nrm, 1e-12f);
    ushort4 o;
    o.x = f2bf(v.x * inv); o.y = f2bf(v.y * inv);
    o.z = f2bf(v.z * inv); o.w = f2bf(v.w * inv);
    reinterpret_cast<ushort4*>(xbf + (size_t)row * K_DIM)[t] = o;
  } else {
    // cast features, grid-stride
    const long n4 = (long)N_FEAT * K_DIM / 4;
    long i = (long)(bid - B_ROWS) * 256 + t;
    const long stride = 2048L * 256;
    for (; i < n4; i += stride) {
      float4 v = reinterpret_cast<const float4*>(f)[i];
      ushort4 o;
      o.x = f2bf(v.x); o.y = f2bf(v.y); o.z = f2bf(v.z); o.w = f2bf(v.w);
      reinterpret_cast<ushort4*>(fbf)[i] = o;
    }
  }
}

// ---------------- K2: target-column logit, one wave per row ----------------
__global__ void k_tgt(const unsigned short* __restrict__ xbf,
                      const unsigned short* __restrict__ fbf,
                      const int* __restrict__ tgt, float* __restrict__ out) {
  int row = blockIdx.x * 4 + (threadIdx.x >> 6);
  int lane = threadIdx.x & 63;
  int t = tgt[row];
  const uint4* xa = reinterpret_cast<const uint4*>(xbf + (size_t)row * K_DIM + lane * 16);
  const uint4* fa = reinterpret_cast<const uint4*>(fbf + (size_t)t * K_DIM + lane * 16);
  float s = 0.f;
  #pragma unroll
  for (int j = 0; j < 2; ++j) {
    uint4 av = xa[j], fv = fa[j];
    const unsigned* ap = &av.x;
    const unsigned* fp = &fv.x;
    #pragma unroll
    for (int q = 0; q < 4; ++q) {
      s += bf2f((unsigned short)(ap[q] & 0xffff)) * bf2f((unsigned short)(fp[q] & 0xffff));
      s += bf2f((unsigned short)(ap[q] >> 16)) * bf2f((unsigned short)(fp[q] >> 16));
    }
  }
  #pragma unroll
  for (int d = 1; d < 64; d <<= 1) s += __shfl_xor(s, d);
  if (lane == 0) out[row] = s * 20.0f;
}

// ---------------- K3: 256x256 8-wave 2-phase-per-Ktile GEMM + fused logsumexp ----
// LDS buf b @ [b*65536]: Ak0 @0, Ak1 @16384, Bk0 @32768, Bk1 @49152.
// Region: [256 rows][32 k] ushort, 64B rows; within-row 16B slot s stored at
// s ^ ((row>>1)&3) (pre-swizzled global source; LDS dest linear).

#define XSTR(s) STR(s)
#define STR(s) #s
#define WAITV(N)  asm volatile("s_waitcnt vmcnt(" XSTR(N) ")" ::: "memory")
#define LGKM0     do { asm volatile("s_waitcnt lgkmcnt(0)" ::: "memory"); __builtin_amdgcn_sched_barrier(0); } while(0)
#define BAR       __builtin_amdgcn_s_barrier()
#define SCHED0    __builtin_amdgcn_sched_barrier(0)
#define PRIO1     __builtin_amdgcn_s_setprio(1)
#define PRIO0     __builtin_amdgcn_s_setprio(0)

__launch_bounds__(512, 2)
__global__ void k_gemm8(const unsigned short* __restrict__ xbf,
                        const unsigned short* __restrict__ fbf,
                        float* __restrict__ m_part, float* __restrict__ l_part) {
  __shared__ __align__(16) char lds_all[131072];
  char* ldsc = lds_all;

  int tid = threadIdx.x;
  int lane = tid & 63;
  int wid = tid >> 6;          // 0..7
  int wr = wid >> 2;           // 0..1
  int wc = wid & 3;            // 0..3
  int r15 = lane & 15;
  int g = lane >> 4;

  // XCD-aware bijective swizzle (2048 blocks % 8 == 0)
  int bid = blockIdx.x;
  int swz = (bid & 7) * 256 + (bid >> 3);
  int mt = swz >> 7;           // 0..15
  int nt = swz & 127;          // 0..127
  int mBase = mt * BM, nBase = nt * BN;

  // fragment-read LDS byte offsets (swizzled slot)
  int lswz = ((g ^ ((r15 >> 1) & 3)) << 4);
  int aRow = (wr * 128 + r15) * 64 + lswz;           // + KH*16384 + fm*1024
  int bRow = (wc * 64 + r15) * 64 + lswz + 32768;    // + KH*16384 + fn*1024

  // staging: per-thread pre-swizzled global source, wave-uniform LDS dest
  int stRow = wid * 32 + (lane >> 2);
  int src_cb = (((lane & 3) ^ ((lane >> 3) & 3)) << 4);
  const char* srcA = (const char*)xbf + (size_t)(mBase + stRow) * (K_DIM * 2) + src_cb;
  const char* srcB = (const char*)fbf + (size_t)(nBase + stRow) * (K_DIM * 2) + src_cb;

#define STAGE(BSEL_, MAT, KH, T) do { \
    const char* gsrc = ((MAT) ? srcB : srcA) + (T) * 128 + (KH) * 64; \
    char* ldst = ldsc + (BSEL_) * 65536 + (MAT) * 32768 + (KH) * 16384 + wid * 2048; \
    __builtin_amdgcn_global_load_lds((const ga_u8*)gsrc, (lds_u8*)ldst, 16, 0, 0); \
    __builtin_amdgcn_global_load_lds((const ga_u8*)(gsrc + 32768), (lds_u8*)(ldst + 1024), 16, 0, 0); \
  } while(0)

// One phase: K=32 half-tile KH of tile T. 12 ds_reads, optional 2-region stage,
// counted vmcnt, barrier, 32 MFMA, barrier.
#define PHASE(T, KH, DOST, SB, SKH, ST, VMN) do { \
    char* bufc = ldsc + ((T) & 1) * 65536 + (KH) * 16384; \
    _Pragma("unroll") \
    for (int fm = 0; fm < 8; ++fm) \
      a[fm] = *reinterpret_cast<const bf16x8*>(bufc + aRow + fm * 1024); \
    _Pragma("unroll") \
    for (int fn = 0; fn < 4; ++fn) \
      b[fn] = *reinterpret_cast<const bf16x8*>(bufc + bRow + fn * 1024); \
    if (DOST) { STAGE(SB, 0, SKH, ST); STAGE(SB, 1, SKH, ST); } \
    WAITV(VMN); \
    BAR; LGKM0; PRIO1; \
    _Pragma("unroll") \
    for (int fm = 0; fm < 8; ++fm) \
      _Pragma("unroll") \
      for (int fn = 0; fn < 4; ++fn) \
        acc[fm][fn] = __builtin_amdgcn_mfma_f32_16x16x32_bf16(a[fm], b[fn], acc[fm][fn], 0, 0, 0); \
    PRIO0; BAR; SCHED0; \
  } while(0)

  f32x4 acc[8][4];
  #pragma unroll
  for (int i = 0; i < 8; ++i)
    #pragma unroll
    for (int j = 0; j < 4; ++j)
      acc[i][j] = (f32x4){0.f, 0.f, 0.f, 0.f};
  bf16x8 a[8], b[4];

  // Prologue (age order matters): k0(0), k1(0), k0(1)
  STAGE(0, 0, 0, 0); STAGE(0, 1, 0, 0);
  STAGE(0, 0, 1, 0); STAGE(0, 1, 1, 0);
  STAGE(1, 0, 0, 1); STAGE(1, 1, 0, 1);
  WAITV(8);          // retires k0(0) pair
  BAR; SCHED0;

  for (int t = 0; t < NKT - 2; ++t) {        // t = 0..13
    PHASE(t, 0, 1, (t + 1) & 1, 1, t + 1, 8);   // stage k1(t+1)
    PHASE(t, 1, 1, t & 1,       0, t + 2, 8);   // stage k0(t+2)
  }
  PHASE(14, 0, 1, 1, 1, 15, 8);               // stage k1(15)
  PHASE(14, 1, 0, 0, 0, 0, 4);
  PHASE(15, 0, 0, 0, 0, 0, 0);
  PHASE(15, 1, 0, 0, 0, 0, 0);

  // ---------------- fused epilogue: per-row max + sumexp over this block's 256 cols
  asm volatile("s_waitcnt vmcnt(0) lgkmcnt(0)" ::: "memory");
  __syncthreads();
  float* sm_m = (float*)lds_all;            // [4][256]
  float* sm_l = (float*)(lds_all + 4096);

  #pragma unroll
  for (int mf = 0; mf < 8; ++mf)
    #pragma unroll
    for (int fn = 0; fn < 4; ++fn)
      acc[mf][fn] = acc[mf][fn] * 20.0f;    // 1/temp

  #pragma unroll
  for (int mf = 0; mf < 8; ++mf) {
    #pragma unroll
    for (int reg = 0; reg < 4; ++reg) {
      float mx = -1e30f;
      #pragma unroll
      for (int fn = 0; fn < 4; ++fn) mx = fmaxf(mx, acc[mf][fn][reg]);
      mx = fmaxf(mx, __shfl_xor(mx, 1));
      mx = fmaxf(mx, __shfl_xor(mx, 2));
      mx = fmaxf(mx, __shfl_xor(mx, 4));
      mx = fmaxf(mx, __shfl_xor(mx, 8));
      float sum = 0.f;
      #pragma unroll
      for (int fn = 0; fn < 4; ++fn) sum += __expf(acc[mf][fn][reg] - mx);
      sum += __shfl_xor(sum, 1);
      sum += __shfl_xor(sum, 2);
      sum += __shfl_xor(sum, 4);
      sum += __shfl_xor(sum, 8);
      if ((lane & 15) == 0) {
        int r = wr * 128 + mf * 16 + (lane >> 4) * 4 + reg;
        sm_m[wc * 256 + r] = mx;
        sm_l[wc * 256 + r] = sum;
      }
    }
  }
  __syncthreads();
  if (tid < 256) {
    float M = sm_m[tid], L = sm_l[tid];
    #pragma unroll
    for (int w = 1; w < 4; ++w) {
      float mo = sm_m[w * 256 + tid], lo = sm_l[w * 256 + tid];
      float mn = fmaxf(M, mo);
      L = L * __expf(M - mn) + lo * __expf(mo - mn);
      M = mn;
    }
    size_t idx = (size_t)(mBase + tid) * NT2 + nt;
    m_part[idx] = M;
    l_part[idx] = L;
  }
}

// ---------------- K4: combine 128 partials per row -> nll -> atomic mean ------
__global__ void k_comb(const float* __restrict__ m_part, const float* __restrict__ l_part,
                       const float* __restrict__ tgt_logit, float* __restrict__ out) {
  int row = blockIdx.x;
  int lane = threadIdx.x;   // 64
  size_t base = (size_t)row * NT2;
  float m = m_part[base + lane];
  float l = l_part[base + lane];
  float m2 = m_part[base + 64 + lane];
  float l2 = l_part[base + 64 + lane];
  float mn = fmaxf(m, m2);
  l = l * __expf(m - mn) + l2 * __expf(m2 - mn);
  m = mn;
  #pragma unroll
  for (int d = 1; d < 64; d <<= 1) {
    float mo = __shfl_xor(m, d);
    float lo = __shfl_xor(l, d);
    float mx = fmaxf(m, mo);
    l = l * __expf(m - mx) + lo * __expf(mo - mx);
    m = mx;
  }
  if (lane == 0) {
    float nll = m + __logf(l) - tgt_logit[row];
    atomicAdd(out, nll * (1.0f / B_ROWS));
  }
}

extern "C" void kernel_launch(void* const* d_in, const int* in_sizes, int n_in,
                              void* d_out, int out_size, void* d_ws, size_t ws_size,
                              hipStream_t stream) {
  const float* inputs = (const float*)d_in[0];
  // d_in[1] = targets (unused by the loss)
  const int* ctgt = (const int*)d_in[2];
  const float* feats = (const float*)d_in[3];
  float* out = (float*)d_out;

  char* ws = (char*)d_ws;
  unsigned short* xbf = (unsigned short*)ws;                          // 8 MB
  unsigned short* fbf = (unsigned short*)(ws + (8ull << 20));         // 64 MB
  float* m_part = (float*)(ws + (72ull << 20));                       // 2 MB
  float* l_part = (float*)(ws + (74ull << 20));                       // 2 MB
  float* tgt_logit = (float*)(ws + (76ull << 20));                    // 16 KB

  hipMemsetAsync(out, 0, sizeof(float), stream);
  k_prep<<<B_ROWS + 2048, 256, 0, stream>>>(inputs, xbf, feats, fbf);
  k_tgt<<<B_ROWS / 4, 256, 0, stream>>>(xbf, fbf, ctgt, tgt_logit);
  k_gemm8<<<(B_ROWS / BM) * (N_FEAT / BN), 512, 0, stream>>>(xbf, fbf, m_part, l_part);
  k_comb<<<B_ROWS, 64, 0, stream>>>(m_part, l_part, tgt_logit, out);
}

// Round 6
// 524.561 us; speedup vs baseline: 1.1420x; 1.1420x over previous
//
#include <hip/hip_runtime.h>
#include <stdint.h>

#define B_ROWS 4096
#define N_FEAT 32768
#define K_DIM  1024
#define BM 256
#define BN 256
#define NT2 (N_FEAT / BN)   // 128 n-tiles

typedef __attribute__((ext_vector_type(8))) short bf16x8;
typedef __attribute__((ext_vector_type(4))) float f32x4;
typedef __attribute__((address_space(1))) unsigned char ga_u8;
typedef __attribute__((address_space(3))) unsigned char lds_u8;

__device__ inline unsigned short f2bf(float f) {
  union { float f; unsigned u; } v; v.f = f;
  unsigned r = v.u + 0x7FFF + ((v.u >> 16) & 1);
  return (unsigned short)(r >> 16);
}
__device__ inline float bf2f(unsigned short u) {
  union { unsigned u; float f; } v; v.u = ((unsigned)u) << 16;
  return v.f;
}

// ---------------- K0: fused {normalize+cast inputs} and {cast features} ----------
__global__ void k_prep(const float* __restrict__ in, unsigned short* __restrict__ xbf,
                       const float* __restrict__ f, unsigned short* __restrict__ fbf) {
  int bid = blockIdx.x;
  int t = threadIdx.x;
  if (bid < B_ROWS) {
    int row = bid;
    float4 v = reinterpret_cast<const float4*>(in + (size_t)row * K_DIM)[t];
    float ssq = v.x * v.x + v.y * v.y + v.z * v.z + v.w * v.w;
    #pragma unroll
    for (int d = 1; d < 64; d <<= 1) ssq += __shfl_xor(ssq, d);
    __shared__ float sm[4];
    if ((t & 63) == 0) sm[t >> 6] = ssq;
    __syncthreads();
    float nrm = sqrtf(sm[0] + sm[1] + sm[2] + sm[3]);
    float inv = 1.0f / fmaxf(nrm, 1e-12f);
    ushort4 o;
    o.x = f2bf(v.x * inv); o.y = f2bf(v.y * inv);
    o.z = f2bf(v.z * inv); o.w = f2bf(v.w * inv);
    reinterpret_cast<ushort4*>(xbf + (size_t)row * K_DIM)[t] = o;
  } else {
    const long n4 = (long)N_FEAT * K_DIM / 4;
    long i = (long)(bid - B_ROWS) * 256 + t;
    const long stride = 8192L * 256;
    for (; i < n4; i += stride) {
      float4 v = reinterpret_cast<const float4*>(f)[i];
      ushort4 o;
      o.x = f2bf(v.x); o.y = f2bf(v.y); o.z = f2bf(v.z); o.w = f2bf(v.w);
      reinterpret_cast<ushort4*>(fbf)[i] = o;
    }
  }
}

// ---------------- K2: target-column logit, one wave per row ----------------
__global__ void k_tgt(const unsigned short* __restrict__ xbf,
                      const unsigned short* __restrict__ fbf,
                      const int* __restrict__ tgt, float* __restrict__ out) {
  int row = blockIdx.x * 4 + (threadIdx.x >> 6);
  int lane = threadIdx.x & 63;
  int t = tgt[row];
  const uint4* xa = reinterpret_cast<const uint4*>(xbf + (size_t)row * K_DIM + lane * 16);
  const uint4* fa = reinterpret_cast<const uint4*>(fbf + (size_t)t * K_DIM + lane * 16);
  float s = 0.f;
  #pragma unroll
  for (int j = 0; j < 2; ++j) {
    uint4 av = xa[j], fv = fa[j];
    const unsigned* ap = &av.x;
    const unsigned* fp = &fv.x;
    #pragma unroll
    for (int q = 0; q < 4; ++q) {
      s += bf2f((unsigned short)(ap[q] & 0xffff)) * bf2f((unsigned short)(fp[q] & 0xffff));
      s += bf2f((unsigned short)(ap[q] >> 16)) * bf2f((unsigned short)(fp[q] >> 16));
    }
  }
  #pragma unroll
  for (int d = 1; d < 64; d <<= 1) s += __shfl_xor(s, d);
  if (lane == 0) out[row] = s * 20.0f;
}

// ---------------- K3: 256x256 8-wave register-double-buffered GEMM + logsumexp ----
// 32 phases, one K=32 half-tile each. 5 LDS slots x 32KB (A 16KB @+0, B 16KB @+16384),
// rotation slot = phase%5, stage depth 4. Per phase:
//   STAGE(half p+4) ; vmcnt(8) ; ds_read frags(p+1)->other reg set ;
//   lgkmcnt(12) [drains only phase p's operand reads] ; 32 MFMA ; barrier.
// MFMA operands were loaded LAST phase -> ds_read latency hidden under MFMA.
// Race-freedom: slot(p+4)==slot(p-1); its readers (phase p-2's ds_reads) drained at
// lgkmcnt in phase p-1, published by BAR(p-1) before the stage issues in phase p.
// Reads of slot(p+1): staged p-3, own-retired at WAITV(8) of p-1, cross-wave via BAR(p-1).

#define XSTR(s) STR(s)
#define STR(s) #s
#define WAITVN(N) asm volatile("s_waitcnt vmcnt(" XSTR(N) ")" ::: "memory")
#define LGKMN(N)  do { asm volatile("s_waitcnt lgkmcnt(" XSTR(N) ")" ::: "memory"); __builtin_amdgcn_sched_barrier(0); } while(0)
#define BAR       __builtin_amdgcn_s_barrier()
#define SCHED0    __builtin_amdgcn_sched_barrier(0)
#define PRIO1     __builtin_amdgcn_s_setprio(1)
#define PRIO0     __builtin_amdgcn_s_setprio(0)

__launch_bounds__(512, 2)
__global__ void k_gemm8(const unsigned short* __restrict__ xbf,
                        const unsigned short* __restrict__ fbf,
                        float* __restrict__ m_part, float* __restrict__ l_part) {
  __shared__ __align__(16) char lds_all[163840];   // 5 slots x 32KB
  char* ldsc = lds_all;

  int tid = threadIdx.x;
  int lane = tid & 63;
  int wid = tid >> 6;          // 0..7
  int wr = wid >> 2;           // 0..1
  int wc = wid & 3;            // 0..3
  int r15 = lane & 15;
  int g = lane >> 4;

  // XCD-aware bijective swizzle (2048 blocks % 8 == 0)
  int bid = blockIdx.x;
  int swz = (bid & 7) * 256 + (bid >> 3);
  int mt = swz >> 7;           // 0..15
  int nt = swz & 127;          // 0..127
  int mBase = mt * BM, nBase = nt * BN;

  // fragment-read LDS byte offsets within a slot (swizzled 16B slot select)
  int lswz = ((g ^ ((r15 >> 1) & 3)) << 4);
  int aOff = (wr * 128 + r15) * 64 + lswz;            // + fm*1024
  int bOff = 16384 + (wc * 64 + r15) * 64 + lswz;     // + fn*1024

  // staging: per-thread pre-swizzled global source, wave-uniform LDS dest
  int stRow = wid * 32 + (lane >> 2);
  int src_cb = (((lane & 3) ^ ((lane >> 3) & 3)) << 4);
  const char* srcA = (const char*)xbf + (size_t)(mBase + stRow) * (K_DIM * 2) + src_cb;
  const char* srcB = (const char*)fbf + (size_t)(nBase + stRow) * (K_DIM * 2) + src_cb;

#define STAGE5(SLOT, H) do { \
    const char* gA = srcA + (H) * 64; \
    char* dA = ldsc + (SLOT) * 32768 + wid * 2048; \
    __builtin_amdgcn_global_load_lds((const ga_u8*)gA, (lds_u8*)dA, 16, 0, 0); \
    __builtin_amdgcn_global_load_lds((const ga_u8*)(gA + 32768), (lds_u8*)(dA + 1024), 16, 0, 0); \
    const char* gB = srcB + (H) * 64; \
    char* dB = ldsc + (SLOT) * 32768 + 16384 + wid * 2048; \
    __builtin_amdgcn_global_load_lds((const ga_u8*)gB, (lds_u8*)dB, 16, 0, 0); \
    __builtin_amdgcn_global_load_lds((const ga_u8*)(gB + 32768), (lds_u8*)(dB + 1024), 16, 0, 0); \
  } while(0)

#define LDF(AA, BB, SLOT) do { \
    char* sb = ldsc + (SLOT) * 32768; \
    _Pragma("unroll") \
    for (int fm = 0; fm < 8; ++fm) \
      AA[fm] = *reinterpret_cast<const bf16x8*>(sb + aOff + fm * 1024); \
    _Pragma("unroll") \
    for (int fn = 0; fn < 4; ++fn) \
      BB[fn] = *reinterpret_cast<const bf16x8*>(sb + bOff + fn * 1024); \
  } while(0)

#define MM5(AA, BB) do { \
    _Pragma("unroll") \
    for (int fm = 0; fm < 8; ++fm) \
      _Pragma("unroll") \
      for (int fn = 0; fn < 4; ++fn) \
        acc[fm][fn] = __builtin_amdgcn_mfma_f32_16x16x32_bf16(AA[fm], BB[fn], acc[fm][fn], 0, 0, 0); \
  } while(0)

// Full phase. DOST: stage half H into SSTG. VM: vmcnt literal. DOLD: load next frags.
// LG: lgkm literal. ACUR/BCUR: compute set. ANXT/BNXT: load target set. SNXT: slot of next frags.
#define PHASE5(SNXT, SSTG, DOST, DOLD, VM, LG, ACUR, BCUR, ANXT, BNXT, H) do { \
    if (DOST) { STAGE5(SSTG, H); } \
    WAITVN(VM); \
    if (DOLD) { LDF(ANXT, BNXT, SNXT); } \
    LGKMN(LG); \
    PRIO1; MM5(ACUR, BCUR); PRIO0; \
    BAR; SCHED0; \
  } while(0)

#define PH_E(SNXT, SSTG, H) PHASE5(SNXT, SSTG, 1, 1, 8, 12, a0, b0, a1, b1, H)
#define PH_O(SNXT, SSTG, H) PHASE5(SNXT, SSTG, 1, 1, 8, 12, a1, b1, a0, b0, H)

  f32x4 acc[8][4];
  #pragma unroll
  for (int i = 0; i < 8; ++i)
    #pragma unroll
    for (int j = 0; j < 4; ++j)
      acc[i][j] = (f32x4){0.f, 0.f, 0.f, 0.f};
  bf16x8 a0[8], b0[4], a1[8], b1[4];

  // Prologue: stage halves 0..3 into slots 0..3; retire 0,1; publish; preload frags(0).
  STAGE5(0, 0); STAGE5(1, 1); STAGE5(2, 2); STAGE5(3, 3);
  WAITVN(8);          // halves 0,1 retired; {2,3} in flight
  BAR; SCHED0;
  LDF(a0, b0, 0);     // 12 lgkm outstanding entering phase 0

  // P0..P27 (steady state)
  PH_E(1, 4, 4);   PH_O(2, 0, 5);   PH_E(3, 1, 6);   PH_O(4, 2, 7);   PH_E(0, 3, 8);
  PH_O(1, 4, 9);   PH_E(2, 0, 10);  PH_O(3, 1, 11);  PH_E(4, 2, 12);  PH_O(0, 3, 13);
  PH_E(1, 4, 14);  PH_O(2, 0, 15);  PH_E(3, 1, 16);  PH_O(4, 2, 17);  PH_E(0, 3, 18);
  PH_O(1, 4, 19);  PH_E(2, 0, 20);  PH_O(3, 1, 21);  PH_E(4, 2, 22);  PH_O(0, 3, 23);
  PH_E(1, 4, 24);  PH_O(2, 0, 25);  PH_E(3, 1, 26);  PH_O(4, 2, 27);  PH_E(0, 3, 28);
  PH_O(1, 4, 29);  PH_E(2, 0, 30);  PH_O(3, 1, 31);
  // Tail: P28..P31 (no staging; drain vmcnt 4->0)
  PHASE5(4, 0, 0, 1, 4, 12, a0, b0, a1, b1, 0);   // P28
  PHASE5(0, 0, 0, 1, 0, 12, a1, b1, a0, b0, 0);   // P29
  PHASE5(1, 0, 0, 1, 0, 12, a0, b0, a1, b1, 0);   // P30
  PHASE5(0, 0, 0, 0, 0, 0,  a1, b1, a0, b0, 0);   // P31

  // ---------------- fused epilogue: per-row max + sumexp over this block's 256 cols
  asm volatile("s_waitcnt vmcnt(0) lgkmcnt(0)" ::: "memory");
  __syncthreads();
  float* sm_m = (float*)lds_all;            // [4][256]
  float* sm_l = (float*)(lds_all + 4096);

  #pragma unroll
  for (int mf = 0; mf < 8; ++mf)
    #pragma unroll
    for (int fn = 0; fn < 4; ++fn)
      acc[mf][fn] = acc[mf][fn] * 20.0f;    // 1/temp

  #pragma unroll
  for (int mf = 0; mf < 8; ++mf) {
    #pragma unroll
    for (int reg = 0; reg < 4; ++reg) {
      float mx = -1e30f;
      #pragma unroll
      for (int fn = 0; fn < 4; ++fn) mx = fmaxf(mx, acc[mf][fn][reg]);
      mx = fmaxf(mx, __shfl_xor(mx, 1));
      mx = fmaxf(mx, __shfl_xor(mx, 2));
      mx = fmaxf(mx, __shfl_xor(mx, 4));
      mx = fmaxf(mx, __shfl_xor(mx, 8));
      float sum = 0.f;
      #pragma unroll
      for (int fn = 0; fn < 4; ++fn) sum += __expf(acc[mf][fn][reg] - mx);
      sum += __shfl_xor(sum, 1);
      sum += __shfl_xor(sum, 2);
      sum += __shfl_xor(sum, 4);
      sum += __shfl_xor(sum, 8);
      if ((lane & 15) == 0) {
        int r = wr * 128 + mf * 16 + (lane >> 4) * 4 + reg;
        sm_m[wc * 256 + r] = mx;
        sm_l[wc * 256 + r] = sum;
      }
    }
  }
  __syncthreads();
  if (tid < 256) {
    float M = sm_m[tid], L = sm_l[tid];
    #pragma unroll
    for (int w = 1; w < 4; ++w) {
      float mo = sm_m[w * 256 + tid], lo = sm_l[w * 256 + tid];
      float mn = fmaxf(M, mo);
      L = L * __expf(M - mn) + lo * __expf(mo - mn);
      M = mn;
    }
    size_t idx = (size_t)(mBase + tid) * NT2 + nt;
    m_part[idx] = M;
    l_part[idx] = L;
  }
}

// ---------------- K4: combine 128 partials per row -> nll (no atomics) ----------
__global__ void k_comb(const float* __restrict__ m_part, const float* __restrict__ l_part,
                       const float* __restrict__ tgt_logit, float* __restrict__ nll) {
  int row = blockIdx.x;
  int lane = threadIdx.x;   // 64
  size_t base = (size_t)row * NT2;
  float m = m_part[base + lane];
  float l = l_part[base + lane];
  float m2 = m_part[base + 64 + lane];
  float l2 = l_part[base + 64 + lane];
  float mn = fmaxf(m, m2);
  l = l * __expf(m - mn) + l2 * __expf(m2 - mn);
  m = mn;
  #pragma unroll
  for (int d = 1; d < 64; d <<= 1) {
    float mo = __shfl_xor(m, d);
    float lo = __shfl_xor(l, d);
    float mx = fmaxf(m, mo);
    l = l * __expf(m - mx) + lo * __expf(mo - mx);
    m = mx;
  }
  if (lane == 0) nll[row] = m + __logf(l) - tgt_logit[row];
}

// ---------------- K5: mean over rows -> out[0] ----------------
__global__ void k_mean(const float* __restrict__ nll, float* __restrict__ out) {
  int t = threadIdx.x;   // 1024
  float s = 0.f;
  #pragma unroll
  for (int i = 0; i < 4; ++i) s += nll[t + i * 1024];
  #pragma unroll
  for (int d = 1; d < 64; d <<= 1) s += __shfl_xor(s, d);
  __shared__ float sm[16];
  if ((t & 63) == 0) sm[t >> 6] = s;
  __syncthreads();
  if (t == 0) {
    float tot = 0.f;
    #pragma unroll
    for (int w = 0; w < 16; ++w) tot += sm[w];
    out[0] = tot * (1.0f / B_ROWS);
  }
}

extern "C" void kernel_launch(void* const* d_in, const int* in_sizes, int n_in,
                              void* d_out, int out_size, void* d_ws, size_t ws_size,
                              hipStream_t stream) {
  const float* inputs = (const float*)d_in[0];
  // d_in[1] = targets (unused by the loss)
  const int* ctgt = (const int*)d_in[2];
  const float* feats = (const float*)d_in[3];
  float* out = (float*)d_out;

  char* ws = (char*)d_ws;
  unsigned short* xbf = (unsigned short*)ws;                          // 8 MB
  unsigned short* fbf = (unsigned short*)(ws + (8ull << 20));         // 64 MB
  float* m_part = (float*)(ws + (72ull << 20));                       // 2 MB
  float* l_part = (float*)(ws + (74ull << 20));                       // 2 MB
  float* tgt_logit = (float*)(ws + (76ull << 20));                    // 16 KB
  float* nll = (float*)(ws + (76ull << 20) + (64ull << 10));          // 16 KB

  k_prep<<<B_ROWS + 8192, 256, 0, stream>>>(inputs, xbf, feats, fbf);
  k_tgt<<<B_ROWS / 4, 256, 0, stream>>>(xbf, fbf, ctgt, tgt_logit);
  k_gemm8<<<(B_ROWS / BM) * (N_FEAT / BN), 512, 0, stream>>>(xbf, fbf, m_part, l_part);
  k_comb<<<B_ROWS, 64, 0, stream>>>(m_part, l_part, tgt_logit, nll);
  k_mean<<<1, 1024, 0, stream>>>(nll, out);
}